// Round 1
// 908.788 us; speedup vs baseline: 1.4457x; 1.4457x over previous
//
#include <hip/hip_runtime.h>
#include <math.h>

#define N_NODES 50000
#define M_ENS   20
#define C_IN    32
#define H       128
#define E_EDGES 800000
#define L_LAYERS 3
#define BN_EPS  1e-5f

typedef unsigned short u16;
typedef unsigned int   u32;

typedef __attribute__((ext_vector_type(8))) short bf16x8;  // 8 bf16 = 4 VGPR
typedef __attribute__((ext_vector_type(4))) float f32x4;

#define MFMA16(a, b, c) __builtin_amdgcn_mfma_f32_16x16x32_bf16((a), (b), (c), 0, 0, 0)

// bf16 helpers (RNE pack, cheap unpack)
__device__ __forceinline__ float bf_lo(u32 p) {
    union { u32 u; float f; } v; v.u = p << 16; return v.f;
}
__device__ __forceinline__ float bf_hi(u32 p) {
    union { u32 u; float f; } v; v.u = p & 0xFFFF0000u; return v.f;
}
__device__ __forceinline__ u16 f2bf(float f) {
    union { float f; u32 u; } v; v.f = f;
    const u32 r = v.u + 0x7FFFu + ((v.u >> 16) & 1u);
    return (u16)(r >> 16);
}
__device__ __forceinline__ float bfu(u16 h) {
    union { u32 u; float f; } v; v.u = (u32)h << 16; return v.f;
}
__device__ __forceinline__ u32 pack2bf(float a, float b) {
    return (u32)f2bf(a) | ((u32)f2bf(b) << 16);
}

// ---------------------------------------------------------------------------
// k_fold: precompute folded weights (unchanged).
// ---------------------------------------------------------------------------
__global__ __launch_bounds__(256) void k_fold(
    const float* __restrict__ w2,  const float* __restrict__ b2,
    const float* __restrict__ rw1, const float* __restrict__ rb1,
    const float* __restrict__ rw2, const float* __restrict__ rb2,
    const float* __restrict__ dr_w, const float* __restrict__ dr_b,
    float* __restrict__ Wf1, float* __restrict__ bf1,
    float* __restrict__ Wf2, float* __restrict__ bf2)
{
    const int g = blockIdx.x >> 7;
    const int j = blockIdx.x & 127;
    const int t = threadIdx.x;

    const float* A  = g ? rw2 : w2;
    const float* Bm = g ? (dr_w + C_IN * H) : rw1;

    __shared__ float s_col[H];
    if (t < H) s_col[t] = Bm[t * H + j];
    __syncthreads();

    const int r = t >> 1, q = t & 1;
    const float* arow = &A[r * H + q * 64];
    const float* cp = &s_col[q * 64];
    float acc = 0.f;
    #pragma unroll
    for (int u = 0; u < 64; u += 4) {
        const float4 av = *(const float4*)&arow[u];
        acc = fmaf(av.x, cp[u], acc);
        acc = fmaf(av.y, cp[u + 1], acc);
        acc = fmaf(av.z, cp[u + 2], acc);
        acc = fmaf(av.w, cp[u + 3], acc);
    }
    acc += __shfl_xor(acc, 1);
    if (q == 0) (g ? Wf2 : Wf1)[r * H + j] = acc;

    if (t == 0) {
        float bacc = g ? dr_b[j] : rb1[j];
        const float* bsrc = g ? rb2 : b2;
        const float scale = g ? 1.f : 20.f;
        for (int k = 0; k < H; ++k)
            bacc = fmaf(scale * bsrc[k], s_col[k], bacc);
        (g ? bf2 : bf1)[j] = bacc;
    }
}

// ---------------------------------------------------------------------------
// k_pack: repack mlp_w1/mlp_w2 into MFMA B-fragment order, split-bf16 (hi/lo).
// Layout per (layer, mat): [part(2)][kstep(4)][ntile(8)][lane(64)][8] u16.
//   k = kstep*32 + (lane>>4)*8 + j ;  n = ntile*16 + (lane&15)
// So a wave's B-fragment load is one coalesced dwordx4 per lane.
// ---------------------------------------------------------------------------
__global__ __launch_bounds__(256) void k_pack(
    const float* __restrict__ w1, const float* __restrict__ w2,
    u16* __restrict__ wpk)
{
    const int tid = blockIdx.x * 256 + threadIdx.x;   // 3*2*4*8*64*8 = 98304
    const int j    = tid & 7;
    const int lane = (tid >> 3) & 63;
    const int nt   = (tid >> 9) & 7;
    const int ks   = (tid >> 12) & 3;
    const int mat  = (tid >> 14) & 1;
    const int l    = tid >> 15;
    if (l >= L_LAYERS) return;

    const int k = ks * 32 + (lane >> 4) * 8 + j;
    const int n = nt * 16 + (lane & 15);
    const float* w = (mat ? w2 : w1) + (size_t)l * H * H;
    const float v = w[k * H + n];

    const u16 hi = f2bf(v);
    const float lo = v - bfu(hi);

    u16* base = wpk + ((size_t)(l * 2 + mat)) * 32768;   // 2 parts * 16384
    const int idx = (ks * 8 + nt) * 512 + lane * 8 + j;
    base[idx] = hi;
    base[16384 + idx] = f2bf(lo);
}

// ---------------------------------------------------------------------------
// k_embed: R7 structure (best measured). bf16 h store. (unchanged this round)
// ---------------------------------------------------------------------------
#define ENB 8
__global__ __launch_bounds__(256) void k_embed(
    const float* __restrict__ ensemble, const float* __restrict__ x,
    const float* __restrict__ phi_w1,   const float* __restrict__ phi_b1,
    const float* __restrict__ Wf1, const float* __restrict__ bf1,
    const float* __restrict__ Wf2, const float* __restrict__ bf2,
    const float* __restrict__ dr_w,
    u16* __restrict__ h_out)
{
    const int n0 = blockIdx.x * ENB;
    const int t  = threadIdx.x;
    const int jp = t & 63;  const int j0 = jp * 2;
    const int np = t >> 6;  const int na = np * 2, nb = na + 1;

    __shared__ __align__(16) float s_ens[ENB * M_ENS * C_IN];
    __shared__ __align__(16) float s_h[ENB][H];
    __shared__ __align__(16) float s_t[ENB][H];
    __shared__ __align__(16) float s_x[ENB][C_IN];

    for (int i = t; i < ENB * M_ENS * C_IN; i += 256)
        s_ens[i] = ensemble[(size_t)n0 * (M_ENS * C_IN) + i];
    s_x[t >> 5][t & 31] = x[(size_t)n0 * C_IN + t];
    __syncthreads();

    float w1a[C_IN], w1b[C_IN];
    #pragma unroll
    for (int k = 0; k < C_IN; ++k) {
        w1a[k] = phi_w1[k * H + j0];
        w1b[k] = phi_w1[k * H + j0 + 1];
    }
    const float b1a = phi_b1[j0], b1b = phi_b1[j0 + 1];

    float hs00 = 0.f, hs01 = 0.f, hs10 = 0.f, hs11 = 0.f;
    for (int m = 0; m < M_ENS; ++m) {
        float a00 = b1a, a01 = b1b, a10 = b1a, a11 = b1b;
        const float* ea = &s_ens[(na * M_ENS + m) * C_IN];
        const float* eb = &s_ens[(nb * M_ENS + m) * C_IN];
        #pragma unroll
        for (int k = 0; k < C_IN; k += 4) {
            const float4 e0 = *(const float4*)&ea[k];
            const float4 e1 = *(const float4*)&eb[k];
            a00 = fmaf(e0.x, w1a[k],   a00); a01 = fmaf(e0.x, w1b[k],   a01);
            a10 = fmaf(e1.x, w1a[k],   a10); a11 = fmaf(e1.x, w1b[k],   a11);
            a00 = fmaf(e0.y, w1a[k+1], a00); a01 = fmaf(e0.y, w1b[k+1], a01);
            a10 = fmaf(e1.y, w1a[k+1], a10); a11 = fmaf(e1.y, w1b[k+1], a11);
            a00 = fmaf(e0.z, w1a[k+2], a00); a01 = fmaf(e0.z, w1b[k+2], a01);
            a10 = fmaf(e1.z, w1a[k+2], a10); a11 = fmaf(e1.z, w1b[k+2], a11);
            a00 = fmaf(e0.w, w1a[k+3], a00); a01 = fmaf(e0.w, w1b[k+3], a01);
            a10 = fmaf(e1.w, w1a[k+3], a10); a11 = fmaf(e1.w, w1b[k+3], a11);
        }
        hs00 += fmaxf(a00, 0.f); hs01 += fmaxf(a01, 0.f);
        hs10 += fmaxf(a10, 0.f); hs11 += fmaxf(a11, 0.f);
    }
    s_h[na][j0] = hs00; s_h[na][j0 + 1] = hs01;
    s_h[nb][j0] = hs10; s_h[nb][j0 + 1] = hs11;
    __syncthreads();

    {
        const float2 bf = *(const float2*)&bf1[j0];
        float a00 = bf.x, a01 = bf.y, a10 = bf.x, a11 = bf.y;
        for (int k = 0; k < H; k += 4) {
            const float2 w0 = *(const float2*)&Wf1[(k    ) * H + j0];
            const float2 w1v= *(const float2*)&Wf1[(k + 1) * H + j0];
            const float2 w2v= *(const float2*)&Wf1[(k + 2) * H + j0];
            const float2 w3v= *(const float2*)&Wf1[(k + 3) * H + j0];
            const float4 h0 = *(const float4*)&s_h[na][k];
            const float4 h1 = *(const float4*)&s_h[nb][k];
            a00 = fmaf(h0.x, w0.x,  a00); a01 = fmaf(h0.x, w0.y,  a01);
            a10 = fmaf(h1.x, w0.x,  a10); a11 = fmaf(h1.x, w0.y,  a11);
            a00 = fmaf(h0.y, w1v.x, a00); a01 = fmaf(h0.y, w1v.y, a01);
            a10 = fmaf(h1.y, w1v.x, a10); a11 = fmaf(h1.y, w1v.y, a11);
            a00 = fmaf(h0.z, w2v.x, a00); a01 = fmaf(h0.z, w2v.y, a01);
            a10 = fmaf(h1.z, w2v.x, a10); a11 = fmaf(h1.z, w2v.y, a11);
            a00 = fmaf(h0.w, w3v.x, a00); a01 = fmaf(h0.w, w3v.y, a01);
            a10 = fmaf(h1.w, w3v.x, a10); a11 = fmaf(h1.w, w3v.y, a11);
        }
        s_t[na][j0] = fmaxf(a00, 0.f); s_t[na][j0 + 1] = fmaxf(a01, 0.f);
        s_t[nb][j0] = fmaxf(a10, 0.f); s_t[nb][j0 + 1] = fmaxf(a11, 0.f);
    }
    __syncthreads();

    {
        const float2 bf = *(const float2*)&bf2[j0];
        float a00 = bf.x, a01 = bf.y, a10 = bf.x, a11 = bf.y;
        for (int k = 0; k < H; k += 4) {
            const float2 w0 = *(const float2*)&Wf2[(k    ) * H + j0];
            const float2 w1v= *(const float2*)&Wf2[(k + 1) * H + j0];
            const float2 w2v= *(const float2*)&Wf2[(k + 2) * H + j0];
            const float2 w3v= *(const float2*)&Wf2[(k + 3) * H + j0];
            const float4 t0 = *(const float4*)&s_t[na][k];
            const float4 t1 = *(const float4*)&s_t[nb][k];
            a00 = fmaf(t0.x, w0.x,  a00); a01 = fmaf(t0.x, w0.y,  a01);
            a10 = fmaf(t1.x, w0.x,  a10); a11 = fmaf(t1.x, w0.y,  a11);
            a00 = fmaf(t0.y, w1v.x, a00); a01 = fmaf(t0.y, w1v.y, a01);
            a10 = fmaf(t1.y, w1v.x, a10); a11 = fmaf(t1.y, w1v.y, a11);
            a00 = fmaf(t0.z, w2v.x, a00); a01 = fmaf(t0.z, w2v.y, a01);
            a10 = fmaf(t1.z, w2v.x, a10); a11 = fmaf(t1.z, w2v.y, a11);
            a00 = fmaf(t0.w, w3v.x, a00); a01 = fmaf(t0.w, w3v.y, a01);
            a10 = fmaf(t1.w, w3v.x, a10); a11 = fmaf(t1.w, w3v.y, a11);
        }
        #pragma unroll
        for (int k = 0; k < C_IN; k += 4) {
            const float2 w0 = *(const float2*)&dr_w[(k    ) * H + j0];
            const float2 w1v= *(const float2*)&dr_w[(k + 1) * H + j0];
            const float2 w2v= *(const float2*)&dr_w[(k + 2) * H + j0];
            const float2 w3v= *(const float2*)&dr_w[(k + 3) * H + j0];
            const float4 x0 = *(const float4*)&s_x[na][k];
            const float4 x1 = *(const float4*)&s_x[nb][k];
            a00 = fmaf(x0.x, w0.x,  a00); a01 = fmaf(x0.x, w0.y,  a01);
            a10 = fmaf(x1.x, w0.x,  a10); a11 = fmaf(x1.x, w0.y,  a11);
            a00 = fmaf(x0.y, w1v.x, a00); a01 = fmaf(x0.y, w1v.y, a01);
            a10 = fmaf(x1.y, w1v.x, a10); a11 = fmaf(x1.y, w1v.y, a11);
            a00 = fmaf(x0.z, w2v.x, a00); a01 = fmaf(x0.z, w2v.y, a01);
            a10 = fmaf(x1.z, w2v.x, a10); a11 = fmaf(x1.z, w2v.y, a11);
            a00 = fmaf(x0.w, w3v.x, a00); a01 = fmaf(x0.w, w3v.y, a01);
            a10 = fmaf(x1.w, w3v.x, a10); a11 = fmaf(x1.w, w3v.y, a11);
        }
        *(u32*)&h_out[(size_t)(n0 + na) * H + j0] = pack2bf(a00, a01);
        *(u32*)&h_out[(size_t)(n0 + nb) * H + j0] = pack2bf(a10, a11);
    }
}

// ---------------------------------------------------------------------------
// CSR build (unchanged).
// ---------------------------------------------------------------------------
__global__ __launch_bounds__(256) void k_count(
    const int* __restrict__ ei, int* __restrict__ deg)
{
    const int e = blockIdx.x * 256 + threadIdx.x;
    if (e >= E_EDGES) return;
    atomicAdd(&deg[ei[E_EDGES + e]], 1);
}

__global__ __launch_bounds__(1024) void k_scan(
    int* __restrict__ off, int* __restrict__ cursor)
{
    const int t = threadIdx.x;
    const int CHUNK = (N_NODES + 1023) / 1024;
    const int lo = t * CHUNK;
    const int hi = min(lo + CHUNK, N_NODES);

    int mysum = 0;
    for (int i = lo; i < hi; ++i) mysum += off[i];

    __shared__ int s[1024];
    s[t] = mysum;
    __syncthreads();
    for (int d = 1; d < 1024; d <<= 1) {
        int v = (t >= d) ? s[t - d] : 0;
        __syncthreads();
        s[t] += v;
        __syncthreads();
    }
    int running = s[t] - mysum;

    for (int i = lo; i < hi; ++i) {
        const int d = off[i];
        off[i] = running;
        cursor[i] = running;
        running += d;
    }
    if (t == 0) off[N_NODES] = E_EDGES;
}

__global__ __launch_bounds__(256) void k_fill(
    const int* __restrict__ ei, const float* __restrict__ ea,
    int* __restrict__ cursor, int2* __restrict__ csr)
{
    const int e = blockIdx.x * 256 + threadIdx.x;
    if (e >= E_EDGES) return;
    const int dst = ei[E_EDGES + e];
    const int pos = atomicAdd(&cursor[dst], 1);
    csr[pos] = make_int2(ei[e], __float_as_int(ea[e]));
}

// ---------------------------------------------------------------------------
// k_layer v2: gather unchanged; H x H matmuls via split-bf16 MFMA.
//   z = (1+eps)*h + agg  -> split into (z_hi, z_lo) bf16 tiles in LDS
//   t = relu(BN(z @ w1 + b1))      [phase A: 24 MFMA/wave]
//   c = t @ w2 + b2 ; h' = relu(c) (+ residual)   [phase B: 24 MFMA/wave]
// M-tile = 16 rows (8 real nodes + 8 don't-care rows). 4 waves x 2 N-tiles.
// Split product: hi*hi + lo*hi + hi*lo  => rel err ~2^-16 (no accuracy gamble).
// LDS tiles stride 136 u16 (272 B): A-frag reads land 2 lanes/bank (free).
// ---------------------------------------------------------------------------
#define NPB 8
__global__ __launch_bounds__(256) void k_layer(
    const int* __restrict__ off, const int2* __restrict__ csr,
    const u16* __restrict__ h_in, u16* __restrict__ h_out,
    const float* __restrict__ ew, const float* __restrict__ eb,
    const float* __restrict__ eps_p,
    const u16* __restrict__ wh1, const u16* __restrict__ wl1,
    const float* __restrict__ b1, const float* __restrict__ bn_g,
    const float* __restrict__ bn_b, const float* __restrict__ bn_m,
    const float* __restrict__ bn_v,
    const u16* __restrict__ wh2, const u16* __restrict__ wl2,
    const float* __restrict__ b2,
    const int first_layer, const int last_layer,
    const float* __restrict__ aw, const float* __restrict__ ab,
    float* __restrict__ out)
{
    const int n0 = blockIdx.x * NPB;
    const int t  = threadIdx.x;

    __shared__ __align__(16) u16   s_zh[16 * 136];
    __shared__ __align__(16) u16   s_zl[16 * 136];
    __shared__ __align__(16) u16   s_th[16 * 136];
    __shared__ __align__(16) u16   s_tl[16 * 136];
    __shared__ __align__(16) float s_r [NPB * 128];
    __shared__ __align__(16) float s_hd[NPB * 128];

    const float ep1 = 1.f + eps_p[0];

    // ---- phase 1: gather. half-wave owns one node (unchanged structure) ----
    {
        const int lane = t & 63;
        const int half = lane >> 5;
        const int c = (lane & 31) * 4;
        const int np = t >> 6;
        const int q = np * 2 + half;        // node slot within block
        const int n = n0 + q;

        const float4 wv = *(const float4*)&ew[c];
        const float4 bv = *(const float4*)&eb[c];

        int i        = off[n];
        const int hi = off[n + 1];

        float ax0 = 0.f, ay0 = 0.f, az0 = 0.f, aw0 = 0.f;
        float ax1 = 0.f, ay1 = 0.f, az1 = 0.f, aw1 = 0.f;

        for (; i + 7 < hi; i += 8) {
            int2 p[8];
            #pragma unroll
            for (int u = 0; u < 8; ++u) p[u] = csr[i + u];
            uint2 hq[8];
            #pragma unroll
            for (int u = 0; u < 8; ++u)
                hq[u] = *(const uint2*)&h_in[(size_t)p[u].x * H + c];
            #pragma unroll
            for (int u = 0; u < 8; ++u) {
                const float a = __int_as_float(p[u].y);
                const float h0 = bf_lo(hq[u].x), h1 = bf_hi(hq[u].x);
                const float h2 = bf_lo(hq[u].y), h3 = bf_hi(hq[u].y);
                if (u & 1) {
                    ax1 += fmaxf(fmaf(a, wv.x, h0) + bv.x, 0.f);
                    ay1 += fmaxf(fmaf(a, wv.y, h1) + bv.y, 0.f);
                    az1 += fmaxf(fmaf(a, wv.z, h2) + bv.z, 0.f);
                    aw1 += fmaxf(fmaf(a, wv.w, h3) + bv.w, 0.f);
                } else {
                    ax0 += fmaxf(fmaf(a, wv.x, h0) + bv.x, 0.f);
                    ay0 += fmaxf(fmaf(a, wv.y, h1) + bv.y, 0.f);
                    az0 += fmaxf(fmaf(a, wv.z, h2) + bv.z, 0.f);
                    aw0 += fmaxf(fmaf(a, wv.w, h3) + bv.w, 0.f);
                }
            }
        }
        for (; i < hi; ++i) {
            const int2 p0 = csr[i];
            const uint2 hq = *(const uint2*)&h_in[(size_t)p0.x * H + c];
            const float a0 = __int_as_float(p0.y);
            ax0 += fmaxf(fmaf(a0, wv.x, bf_lo(hq.x)) + bv.x, 0.f);
            ay0 += fmaxf(fmaf(a0, wv.y, bf_hi(hq.x)) + bv.y, 0.f);
            az0 += fmaxf(fmaf(a0, wv.z, bf_lo(hq.y)) + bv.z, 0.f);
            aw0 += fmaxf(fmaf(a0, wv.w, bf_hi(hq.y)) + bv.w, 0.f);
        }
        ax0 += ax1; ay0 += ay1; az0 += az1; aw0 += aw1;

        // own-node h row -> residual + z (split hi/lo bf16 for MFMA A-tiles)
        const uint2 ho = *(const uint2*)&h_in[(size_t)n * H + c];
        const float r0 = bf_lo(ho.x), r1 = bf_hi(ho.x);
        const float r2 = bf_lo(ho.y), r3 = bf_hi(ho.y);
        *(float4*)&s_r[q * 128 + c] = make_float4(r0, r1, r2, r3);

        const float z0 = fmaf(ep1, r0, ax0);
        const float z1 = fmaf(ep1, r1, ay0);
        const float z2 = fmaf(ep1, r2, az0);
        const float z3 = fmaf(ep1, r3, aw0);
        const u16 zh0 = f2bf(z0), zh1 = f2bf(z1), zh2 = f2bf(z2), zh3 = f2bf(z3);
        *(u32*)&s_zh[q * 136 + c]     = (u32)zh0 | ((u32)zh1 << 16);
        *(u32*)&s_zh[q * 136 + c + 2] = (u32)zh2 | ((u32)zh3 << 16);
        *(u32*)&s_zl[q * 136 + c]     = pack2bf(z0 - bfu(zh0), z1 - bfu(zh1));
        *(u32*)&s_zl[q * 136 + c + 2] = pack2bf(z2 - bfu(zh2), z3 - bfu(zh3));
    }
    __syncthreads();

    const int lane = t & 63;
    const int wv   = t >> 6;          // wave 0..3
    const int l15  = lane & 15;       // A row / C col within tile
    const int kl   = lane >> 4;       // k-group (A/B) & row-group (C)
    const int nt0  = wv * 2, nt1 = wv * 2 + 1;
    const int nA   = nt0 * 16 + l15;  // output channel, tile 0
    const int nB   = nt1 * 16 + l15;  // output channel, tile 1

    // ---- phase 2: t = relu(BN(z @ w1 + b1))  [MFMA] ----
    {
        f32x4 acc0 = {0.f, 0.f, 0.f, 0.f};
        f32x4 acc1 = {0.f, 0.f, 0.f, 0.f};
        #pragma unroll
        for (int ks = 0; ks < 4; ++ks) {
            const int aoff = l15 * 136 + ks * 32 + kl * 8;
            const bf16x8 ah = *(const bf16x8*)&s_zh[aoff];
            const bf16x8 al = *(const bf16x8*)&s_zl[aoff];
            const int bo0 = (ks * 8 + nt0) * 512 + lane * 8;
            const int bo1 = (ks * 8 + nt1) * 512 + lane * 8;
            const bf16x8 bh0 = *(const bf16x8*)&wh1[bo0];
            const bf16x8 bl0 = *(const bf16x8*)&wl1[bo0];
            const bf16x8 bh1 = *(const bf16x8*)&wh1[bo1];
            const bf16x8 bl1 = *(const bf16x8*)&wl1[bo1];
            acc0 = MFMA16(ah, bh0, acc0);
            acc0 = MFMA16(al, bh0, acc0);
            acc0 = MFMA16(ah, bl0, acc0);
            acc1 = MFMA16(ah, bh1, acc1);
            acc1 = MFMA16(al, bh1, acc1);
            acc1 = MFMA16(ah, bl1, acc1);
        }
        // BN fold: t = y*sc + sh, sc = g*rsqrt(v+eps), sh = (b1-m)*sc + b
        const float sc0 = bn_g[nA] * rsqrtf(bn_v[nA] + BN_EPS);
        const float sh0 = fmaf(b1[nA] - bn_m[nA], sc0, bn_b[nA]);
        const float sc1 = bn_g[nB] * rsqrtf(bn_v[nB] + BN_EPS);
        const float sh1 = fmaf(b1[nB] - bn_m[nB], sc1, bn_b[nB]);

        if (kl < 2) {                  // rows 0..7 are real nodes
            #pragma unroll
            for (int r = 0; r < 4; ++r) {
                const int m = kl * 4 + r;
                const float t0 = fmaxf(fmaf(acc0[r], sc0, sh0), 0.f);
                const float t1 = fmaxf(fmaf(acc1[r], sc1, sh1), 0.f);
                const u16 th0 = f2bf(t0), th1 = f2bf(t1);
                s_th[m * 136 + nA] = th0;
                s_tl[m * 136 + nA] = f2bf(t0 - bfu(th0));
                s_th[m * 136 + nB] = th1;
                s_tl[m * 136 + nB] = f2bf(t1 - bfu(th1));
            }
        }
    }
    __syncthreads();

    // ---- phase 3: c = t @ w2 + b2; h' = relu(c) (+res); store / head ----
    {
        f32x4 acc0 = {0.f, 0.f, 0.f, 0.f};
        f32x4 acc1 = {0.f, 0.f, 0.f, 0.f};
        #pragma unroll
        for (int ks = 0; ks < 4; ++ks) {
            const int aoff = l15 * 136 + ks * 32 + kl * 8;
            const bf16x8 ah = *(const bf16x8*)&s_th[aoff];
            const bf16x8 al = *(const bf16x8*)&s_tl[aoff];
            const int bo0 = (ks * 8 + nt0) * 512 + lane * 8;
            const int bo1 = (ks * 8 + nt1) * 512 + lane * 8;
            const bf16x8 bh0 = *(const bf16x8*)&wh2[bo0];
            const bf16x8 bl0 = *(const bf16x8*)&wl2[bo0];
            const bf16x8 bh1 = *(const bf16x8*)&wh2[bo1];
            const bf16x8 bl1 = *(const bf16x8*)&wl2[bo1];
            acc0 = MFMA16(ah, bh0, acc0);
            acc0 = MFMA16(al, bh0, acc0);
            acc0 = MFMA16(ah, bl0, acc0);
            acc1 = MFMA16(ah, bh1, acc1);
            acc1 = MFMA16(al, bh1, acc1);
            acc1 = MFMA16(ah, bl1, acc1);
        }
        const float bb0 = b2[nA];
        const float bb1 = b2[nB];

        if (kl < 2) {
            #pragma unroll
            for (int r = 0; r < 4; ++r) {
                const int m = kl * 4 + r;
                float h0 = fmaxf(acc0[r] + bb0, 0.f);
                float h1 = fmaxf(acc1[r] + bb1, 0.f);
                if (!first_layer) {
                    h0 += s_r[m * 128 + nA];
                    h1 += s_r[m * 128 + nB];
                }
                if (!last_layer) {
                    h_out[(size_t)(n0 + m) * H + nA] = f2bf(h0);
                    h_out[(size_t)(n0 + m) * H + nB] = f2bf(h1);
                } else {
                    s_hd[m * 128 + nA] = h0;
                    s_hd[m * 128 + nB] = h1;
                }
            }
        }
    }

    if (last_layer) {
        __syncthreads();
        // head: out = h @ aw + ab; mu, softplus(sigma). 64 lanes hold
        // channels j0,j0+1 of nodes na,nb -> shfl reduce (as before).
        const int jp = t & 63;  const int j0 = jp * 2;
        const int np = t >> 6;  const int na = np * 2, nb = na + 1;
        const float2 ha  = *(const float2*)&s_hd[na * 128 + j0];
        const float2 hbv = *(const float2*)&s_hd[nb * 128 + j0];
        const float2 awx = *(const float2*)&aw[j0 * 2];          // ch j0
        const float2 awy = *(const float2*)&aw[(j0 + 1) * 2];    // ch j0+1
        float mu_a = ha.x  * awx.x + ha.y  * awy.x;
        float sg_a = ha.x  * awx.y + ha.y  * awy.y;
        float mu_b = hbv.x * awx.x + hbv.y * awy.x;
        float sg_b = hbv.x * awx.y + hbv.y * awy.y;
        #pragma unroll
        for (int sft = 32; sft > 0; sft >>= 1) {
            mu_a += __shfl_down(mu_a, sft);
            sg_a += __shfl_down(sg_a, sft);
            mu_b += __shfl_down(mu_b, sft);
            sg_b += __shfl_down(sg_b, sft);
        }
        if (jp == 0) {
            const float o1a = sg_a + ab[1];
            const float o1b = sg_b + ab[1];
            const float spa = (o1a > 0.f) ? (o1a + log1pf(expf(-o1a)))
                                          : log1pf(expf(o1a));
            const float spb = (o1b > 0.f) ? (o1b + log1pf(expf(-o1b)))
                                          : log1pf(expf(o1b));
            out[(size_t)(n0 + na) * 2 + 0] = mu_a + ab[0];
            out[(size_t)(n0 + na) * 2 + 1] = spa;
            out[(size_t)(n0 + nb) * 2 + 0] = mu_b + ab[0];
            out[(size_t)(n0 + nb) * 2 + 1] = spb;
        }
    }
}

// ---------------------------------------------------------------------------
extern "C" void kernel_launch(void* const* d_in, const int* in_sizes, int n_in,
                              void* d_out, int out_size, void* d_ws, size_t ws_size,
                              hipStream_t stream)
{
    const float* ensemble = (const float*)d_in[0];
    const float* x        = (const float*)d_in[1];
    const int*   ei       = (const int*)d_in[2];
    const float* ea       = (const float*)d_in[3];
    const float* phi_w1   = (const float*)d_in[4];
    const float* phi_b1   = (const float*)d_in[5];
    const float* phi_w2   = (const float*)d_in[6];
    const float* phi_b2   = (const float*)d_in[7];
    const float* rho_w1   = (const float*)d_in[8];
    const float* rho_b1   = (const float*)d_in[9];
    const float* rho_w2   = (const float*)d_in[10];
    const float* rho_b2   = (const float*)d_in[11];
    const float* dr_w     = (const float*)d_in[12];
    const float* dr_b     = (const float*)d_in[13];
    const float* conv_eps = (const float*)d_in[14];
    const float* edge_w   = (const float*)d_in[15];
    const float* edge_b   = (const float*)d_in[16];
    const float* mlp_w1   = (const float*)d_in[17];
    const float* mlp_b1   = (const float*)d_in[18];
    const float* bn_g     = (const float*)d_in[19];
    const float* bn_b     = (const float*)d_in[20];
    const float* bn_m     = (const float*)d_in[21];
    const float* bn_v     = (const float*)d_in[22];
    const float* mlp_w2   = (const float*)d_in[23];
    const float* mlp_b2   = (const float*)d_in[24];
    const float* aggr_w   = (const float*)d_in[25];
    const float* aggr_b   = (const float*)d_in[26];

    float* out = (float*)d_out;

    // workspace layout
    float* Wf1     = (float*)d_ws;                          // H*H
    float* bf1     = Wf1 + H * H;                           // H
    float* Wf2     = bf1 + H;                               // H*H
    float* bf2     = Wf2 + H * H;                           // H
    int*   off     = (int*)(bf2 + H);                       // N+2 (padded)
    int*   cursor  = off + (N_NODES + 2);                   // N
    int2*  csr     = (int2*)(cursor + N_NODES);             // E (8B aligned)
    u16*   h_a     = (u16*)(csr + E_EDGES);                 // N*H bf16
    u16*   h_b     = h_a + (size_t)N_NODES * H;             // N*H bf16
    u16*   wpk     = h_b + (size_t)N_NODES * H;             // L*2*2*16384 u16

    const int eblocks = (E_EDGES + 255) / 256;

    // fold weights, pack MFMA weights, then embed -> h_a
    k_fold<<<256, 256, 0, stream>>>(phi_w2, phi_b2, rho_w1, rho_b1,
                                    rho_w2, rho_b2, dr_w, dr_b,
                                    Wf1, bf1, Wf2, bf2);
    k_pack<<<384, 256, 0, stream>>>(mlp_w1, mlp_w2, wpk);
    k_embed<<<N_NODES / ENB, 256, 0, stream>>>(
        ensemble, x, phi_w1, phi_b1, Wf1, bf1, Wf2, bf2, dr_w, h_a);

    // CSR build (once)
    hipMemsetAsync(off, 0, (N_NODES + 1) * sizeof(int), stream);
    k_count<<<eblocks, 256, 0, stream>>>(ei, off);
    k_scan<<<1, 1024, 0, stream>>>(off, cursor);
    k_fill<<<eblocks, 256, 0, stream>>>(ei, ea, cursor, csr);

    // fused GINE layers (double-buffered h; last layer writes head to out)
    u16* hin = h_a; u16* hout = h_b;
    for (int i = 0; i < L_LAYERS; ++i) {
        const u16* wh1 = wpk + ((size_t)i * 2 + 0) * 32768;
        const u16* wl1 = wh1 + 16384;
        const u16* wh2 = wpk + ((size_t)i * 2 + 1) * 32768;
        const u16* wl2 = wh2 + 16384;
        k_layer<<<N_NODES / NPB, 256, 0, stream>>>(
            off, csr, hin, hout,
            edge_w + (size_t)i * H, edge_b + (size_t)i * H, conv_eps + i,
            wh1, wl1,
            mlp_b1 + (size_t)i * H,
            bn_g + (size_t)i * H, bn_b + (size_t)i * H,
            bn_m + (size_t)i * H, bn_v + (size_t)i * H,
            wh2, wl2, mlp_b2 + (size_t)i * H,
            (i == 0) ? 1 : 0, (i == L_LAYERS - 1) ? 1 : 0,
            aggr_w, aggr_b, out);
        u16* tmp = hin; hin = hout; hout = tmp;
    }
}

// Round 2
// 711.717 us; speedup vs baseline: 1.8460x; 1.2769x over previous
//
#include <hip/hip_runtime.h>
#include <math.h>

#define N_NODES 50000
#define M_ENS   20
#define C_IN    32
#define H       128
#define E_EDGES 800000
#define L_LAYERS 3
#define BN_EPS  1e-5f

typedef unsigned short u16;
typedef unsigned int   u32;

typedef __attribute__((ext_vector_type(8))) short bf16x8;  // 8 bf16 = 4 VGPR
typedef __attribute__((ext_vector_type(4))) float f32x4;

#define MFMA16(a, b, c) __builtin_amdgcn_mfma_f32_16x16x32_bf16((a), (b), (c), 0, 0, 0)

// bf16 helpers (RNE pack, cheap unpack)
__device__ __forceinline__ float bf_lo(u32 p) {
    union { u32 u; float f; } v; v.u = p << 16; return v.f;
}
__device__ __forceinline__ float bf_hi(u32 p) {
    union { u32 u; float f; } v; v.u = p & 0xFFFF0000u; return v.f;
}
__device__ __forceinline__ u16 f2bf(float f) {
    union { float f; u32 u; } v; v.f = f;
    const u32 r = v.u + 0x7FFFu + ((v.u >> 16) & 1u);
    return (u16)(r >> 16);
}
__device__ __forceinline__ float bfu(u16 h) {
    union { u32 u; float f; } v; v.u = (u32)h << 16; return v.f;
}
__device__ __forceinline__ u32 pack2bf(float a, float b) {
    return (u32)f2bf(a) | ((u32)f2bf(b) << 16);
}

// split f32[8] -> (hi, lo) bf16x8 fragments
__device__ __forceinline__ void split8(const float* a, bf16x8& h, bf16x8& l) {
    #pragma unroll
    for (int j = 0; j < 8; ++j) {
        const u16 hv = f2bf(a[j]);
        h[j] = (short)hv;
        l[j] = (short)f2bf(a[j] - bfu(hv));
    }
}

// ---------------------------------------------------------------------------
// k_fold: precompute folded weights (unchanged).
// ---------------------------------------------------------------------------
__global__ __launch_bounds__(256) void k_fold(
    const float* __restrict__ w2,  const float* __restrict__ b2,
    const float* __restrict__ rw1, const float* __restrict__ rb1,
    const float* __restrict__ rw2, const float* __restrict__ rb2,
    const float* __restrict__ dr_w, const float* __restrict__ dr_b,
    float* __restrict__ Wf1, float* __restrict__ bf1,
    float* __restrict__ Wf2, float* __restrict__ bf2)
{
    const int g = blockIdx.x >> 7;
    const int j = blockIdx.x & 127;
    const int t = threadIdx.x;

    const float* A  = g ? rw2 : w2;
    const float* Bm = g ? (dr_w + C_IN * H) : rw1;

    __shared__ float s_col[H];
    if (t < H) s_col[t] = Bm[t * H + j];
    __syncthreads();

    const int r = t >> 1, q = t & 1;
    const float* arow = &A[r * H + q * 64];
    const float* cp = &s_col[q * 64];
    float acc = 0.f;
    #pragma unroll
    for (int u = 0; u < 64; u += 4) {
        const float4 av = *(const float4*)&arow[u];
        acc = fmaf(av.x, cp[u], acc);
        acc = fmaf(av.y, cp[u + 1], acc);
        acc = fmaf(av.z, cp[u + 2], acc);
        acc = fmaf(av.w, cp[u + 3], acc);
    }
    acc += __shfl_xor(acc, 1);
    if (q == 0) (g ? Wf2 : Wf1)[r * H + j] = acc;

    if (t == 0) {
        float bacc = g ? dr_b[j] : rb1[j];
        const float* bsrc = g ? rb2 : b2;
        const float scale = g ? 1.f : 20.f;
        for (int k = 0; k < H; ++k)
            bacc = fmaf(scale * bsrc[k], s_col[k], bacc);
        (g ? bf2 : bf1)[j] = bacc;
    }
}

// ---------------------------------------------------------------------------
// k_pack: repack mlp_w1/mlp_w2 into MFMA B-fragment order, split-bf16 (hi/lo).
// Layout per (layer, mat): [part(2)][kstep(4)][ntile(8)][lane(64)][8] u16.
//   k = kstep*32 + (lane>>4)*8 + j ;  n = ntile*16 + (lane&15)
// ---------------------------------------------------------------------------
__global__ __launch_bounds__(256) void k_pack(
    const float* __restrict__ w1, const float* __restrict__ w2,
    u16* __restrict__ wpk)
{
    const int tid = blockIdx.x * 256 + threadIdx.x;   // 3*2*4*8*64*8 = 98304
    const int j    = tid & 7;
    const int lane = (tid >> 3) & 63;
    const int nt   = (tid >> 9) & 7;
    const int ks   = (tid >> 12) & 3;
    const int mat  = (tid >> 14) & 1;
    const int l    = tid >> 15;
    if (l >= L_LAYERS) return;

    const int k = ks * 32 + (lane >> 4) * 8 + j;
    const int n = nt * 16 + (lane & 15);
    const float* w = (mat ? w2 : w1) + (size_t)l * H * H;
    const float v = w[k * H + n];

    const u16 hi = f2bf(v);
    const float lo = v - bfu(hi);

    u16* base = wpk + ((size_t)(l * 2 + mat)) * 32768;   // 2 parts * 16384
    const int idx = (ks * 8 + nt) * 512 + lane * 8 + j;
    base[idx] = hi;
    base[16384 + idx] = f2bf(lo);
}

// ---------------------------------------------------------------------------
// k_pack2: pack embed-path weights into MFMA B-fragment order, split hi/lo.
//   phi_w1 (32x128, KS=1), Wf1 (128x128, KS=4), Wf2 (128x128, KS=4),
//   dr_w rows 0..31 (x-part, KS=1). Runs AFTER k_fold (reads Wf1/Wf2).
// u16 offsets inside pk:
//   phi: hi 0      lo 4096
//   Wf1: hi 8192   lo 24576
//   Wf2: hi 40960  lo 57344
//   dr : hi 73728  lo 77824     (total 81920 u16)
// ---------------------------------------------------------------------------
#define PW1H 0
#define PW1L 4096
#define WF1H 8192
#define WF1L 24576
#define WF2H 40960
#define WF2L 57344
#define DRH  73728
#define DRL  77824
__global__ __launch_bounds__(256) void k_pack2(
    const float* __restrict__ phi_w1, const float* __restrict__ Wf1,
    const float* __restrict__ Wf2,    const float* __restrict__ dr_w,
    u16* __restrict__ pk)
{
    const int tid = blockIdx.x * 256 + threadIdx.x;   // 40960 total
    int idx; const float* src; int bh; int bl;
    if (tid < 4096)       { idx = tid;         src = phi_w1; bh = PW1H; bl = PW1L; }
    else if (tid < 20480) { idx = tid - 4096;  src = Wf1;    bh = WF1H; bl = WF1L; }
    else if (tid < 36864) { idx = tid - 20480; src = Wf2;    bh = WF2H; bl = WF2L; }
    else if (tid < 40960) { idx = tid - 36864; src = dr_w;   bh = DRH;  bl = DRL;  }
    else return;

    const int j    = idx & 7;
    const int lane = (idx >> 3) & 63;
    const int nt   = (idx >> 9) & 7;
    const int ks   = idx >> 12;
    const int k = ks * 32 + (lane >> 4) * 8 + j;
    const int n = nt * 16 + (lane & 15);
    const float v = src[k * H + n];
    const u16 hi = f2bf(v);
    pk[bh + idx] = hi;
    pk[bl + idx] = f2bf(v - bfu(hi));
}

// ---------------------------------------------------------------------------
// k_embed v2: full MFMA.
// Block = 16 nodes (320 ensemble rows). Wave w owns nodes 4w..4w+3 =
// 80 rows = 5 M-tiles of 16x32 (K=32=C_IN in one mfma step).
// A-tile row permutation: slot s -> node = s&3, mgrp = s>>2; tile t -> m =
// mgrp*5 + t. Then C rows (lane>>4)*4+reg give node = reg (STATIC) and
// mgrp = lane>>4, so relu-accumulation acc[reg][nt] is all-static; the
// m-sum finishes with shfl_xor(16)+shfl_xor(32) butterflies.
// A-frags built in registers from global (exactly-once 128 MB, no LDS).
// Phases 2/3: k_layer-style MFMA over s_h / s_t split tiles; x-part of
// dr_w as a K=32 register A-frag. Split-bf16 (hi*hi+lo*hi+hi*lo) all over.
// ---------------------------------------------------------------------------
#define ENB 16
__global__ __launch_bounds__(256) void k_embed(
    const float* __restrict__ ensemble, const float* __restrict__ x,
    const float* __restrict__ phi_b1,
    const float* __restrict__ bf1, const float* __restrict__ bf2,
    const u16* __restrict__ pk,
    u16* __restrict__ h_out)
{
    const int n0 = blockIdx.x * ENB;
    const int t  = threadIdx.x;
    const int lane = t & 63;
    const int w    = t >> 6;
    const int l15  = lane & 15;
    const int kl   = lane >> 4;

    __shared__ __align__(16) u16 s_hh[16 * 136], s_hl[16 * 136];
    __shared__ __align__(16) u16 s_th[16 * 136], s_tl[16 * 136];

    // phi B fragments: resident in VGPRs across all 5 M-tiles
    bf16x8 pbh[8], pbl[8];
    #pragma unroll
    for (int nt = 0; nt < 8; ++nt) {
        pbh[nt] = *(const bf16x8*)&pk[PW1H + nt * 512 + lane * 8];
        pbl[nt] = *(const bf16x8*)&pk[PW1L + nt * 512 + lane * 8];
    }
    float b1v[8];
    #pragma unroll
    for (int nt = 0; nt < 8; ++nt) b1v[nt] = phi_b1[nt * 16 + l15];

    // ---- phase 1: phi = sum_m relu(ens @ phi_w1 + b1)  [MFMA] ----
    // ensemble A loads: lane row = (node = l15&3, mgrp = l15>>2), k = kl*8..+7
    const float* ebase = ensemble
        + ((size_t)(n0 + w * 4 + (l15 & 3)) * M_ENS + (l15 >> 2) * 5) * C_IN
        + kl * 8;
    float4 av[5][2];
    #pragma unroll
    for (int tt = 0; tt < 5; ++tt) {
        av[tt][0] = *(const float4*)(ebase + tt * C_IN);
        av[tt][1] = *(const float4*)(ebase + tt * C_IN + 4);
    }

    float acc[4][8];
    #pragma unroll
    for (int r = 0; r < 4; ++r)
        #pragma unroll
        for (int nt = 0; nt < 8; ++nt) acc[r][nt] = 0.f;

    #pragma unroll
    for (int tt = 0; tt < 5; ++tt) {
        float a8[8] = {av[tt][0].x, av[tt][0].y, av[tt][0].z, av[tt][0].w,
                       av[tt][1].x, av[tt][1].y, av[tt][1].z, av[tt][1].w};
        bf16x8 ah, al;
        split8(a8, ah, al);
        #pragma unroll
        for (int nt = 0; nt < 8; ++nt) {
            f32x4 c = {0.f, 0.f, 0.f, 0.f};
            c = MFMA16(ah, pbh[nt], c);
            c = MFMA16(al, pbh[nt], c);
            c = MFMA16(ah, pbl[nt], c);
            #pragma unroll
            for (int r = 0; r < 4; ++r)
                acc[r][nt] += fmaxf(c[r] + b1v[nt], 0.f);
        }
    }

    // m-sum across the 4 kl groups (each holds 5 of the 20 members)
    #pragma unroll
    for (int r = 0; r < 4; ++r)
        #pragma unroll
        for (int nt = 0; nt < 8; ++nt) {
            float v = acc[r][nt];
            v += __shfl_xor(v, 16);
            v += __shfl_xor(v, 32);
            acc[r][nt] = v;
        }

    // write split s_h rows 4w+r (kl group r writes node r; static acc index)
    #pragma unroll
    for (int r = 0; r < 4; ++r) {
        if (kl == r) {
            const int row = w * 4 + r;
            #pragma unroll
            for (int nt = 0; nt < 8; ++nt) {
                const float v = acc[r][nt];
                const u16 hv = f2bf(v);
                s_hh[row * 136 + nt * 16 + l15] = hv;
                s_hl[row * 136 + nt * 16 + l15] = f2bf(v - bfu(hv));
            }
        }
    }
    __syncthreads();

    // phase-3 x A-frag loads issued now (hide under phase 2 MFMAs)
    const float* xb = x + (size_t)(n0 + l15) * C_IN + kl * 8;
    const float4 xv0 = *(const float4*)xb;
    const float4 xv1 = *(const float4*)(xb + 4);

    const int nt0 = w * 2, nt1 = nt0 + 1;
    const int nA = nt0 * 16 + l15, nB = nt1 * 16 + l15;

    // ---- phase 2: t = relu(s_h @ Wf1 + bf1)  [MFMA] ----
    {
        f32x4 acc0 = {0.f, 0.f, 0.f, 0.f};
        f32x4 acc1 = {0.f, 0.f, 0.f, 0.f};
        #pragma unroll
        for (int ks = 0; ks < 4; ++ks) {
            const int aoff = l15 * 136 + ks * 32 + kl * 8;
            const bf16x8 ah = *(const bf16x8*)&s_hh[aoff];
            const bf16x8 al = *(const bf16x8*)&s_hl[aoff];
            const int bo0 = (ks * 8 + nt0) * 512 + lane * 8;
            const int bo1 = (ks * 8 + nt1) * 512 + lane * 8;
            const bf16x8 bh0 = *(const bf16x8*)&pk[WF1H + bo0];
            const bf16x8 bl0 = *(const bf16x8*)&pk[WF1L + bo0];
            const bf16x8 bh1 = *(const bf16x8*)&pk[WF1H + bo1];
            const bf16x8 bl1 = *(const bf16x8*)&pk[WF1L + bo1];
            acc0 = MFMA16(ah, bh0, acc0);
            acc0 = MFMA16(al, bh0, acc0);
            acc0 = MFMA16(ah, bl0, acc0);
            acc1 = MFMA16(ah, bh1, acc1);
            acc1 = MFMA16(al, bh1, acc1);
            acc1 = MFMA16(ah, bl1, acc1);
        }
        const float bA = bf1[nA], bB = bf1[nB];
        #pragma unroll
        for (int r = 0; r < 4; ++r) {
            const int m = kl * 4 + r;
            const float t0 = fmaxf(acc0[r] + bA, 0.f);
            const float t1 = fmaxf(acc1[r] + bB, 0.f);
            const u16 h0 = f2bf(t0), h1 = f2bf(t1);
            s_th[m * 136 + nA] = h0;
            s_tl[m * 136 + nA] = f2bf(t0 - bfu(h0));
            s_th[m * 136 + nB] = h1;
            s_tl[m * 136 + nB] = f2bf(t1 - bfu(h1));
        }
    }
    __syncthreads();

    // ---- phase 3: h = s_t @ Wf2 + x @ dr_up + bf2 ----
    {
        f32x4 acc0 = {0.f, 0.f, 0.f, 0.f};
        f32x4 acc1 = {0.f, 0.f, 0.f, 0.f};
        #pragma unroll
        for (int ks = 0; ks < 4; ++ks) {
            const int aoff = l15 * 136 + ks * 32 + kl * 8;
            const bf16x8 ah = *(const bf16x8*)&s_th[aoff];
            const bf16x8 al = *(const bf16x8*)&s_tl[aoff];
            const int bo0 = (ks * 8 + nt0) * 512 + lane * 8;
            const int bo1 = (ks * 8 + nt1) * 512 + lane * 8;
            const bf16x8 bh0 = *(const bf16x8*)&pk[WF2H + bo0];
            const bf16x8 bl0 = *(const bf16x8*)&pk[WF2L + bo0];
            const bf16x8 bh1 = *(const bf16x8*)&pk[WF2H + bo1];
            const bf16x8 bl1 = *(const bf16x8*)&pk[WF2L + bo1];
            acc0 = MFMA16(ah, bh0, acc0);
            acc0 = MFMA16(al, bh0, acc0);
            acc0 = MFMA16(ah, bl0, acc0);
            acc1 = MFMA16(ah, bh1, acc1);
            acc1 = MFMA16(al, bh1, acc1);
            acc1 = MFMA16(ah, bl1, acc1);
        }
        // x part (K=32, one kstep)
        {
            float x8[8] = {xv0.x, xv0.y, xv0.z, xv0.w,
                           xv1.x, xv1.y, xv1.z, xv1.w};
            bf16x8 xh, xl;
            split8(x8, xh, xl);
            const bf16x8 dh0 = *(const bf16x8*)&pk[DRH + nt0 * 512 + lane * 8];
            const bf16x8 dl0 = *(const bf16x8*)&pk[DRL + nt0 * 512 + lane * 8];
            const bf16x8 dh1 = *(const bf16x8*)&pk[DRH + nt1 * 512 + lane * 8];
            const bf16x8 dl1 = *(const bf16x8*)&pk[DRL + nt1 * 512 + lane * 8];
            acc0 = MFMA16(xh, dh0, acc0);
            acc0 = MFMA16(xl, dh0, acc0);
            acc0 = MFMA16(xh, dl0, acc0);
            acc1 = MFMA16(xh, dh1, acc1);
            acc1 = MFMA16(xl, dh1, acc1);
            acc1 = MFMA16(xh, dl1, acc1);
        }
        const float bA = bf2[nA], bB = bf2[nB];
        #pragma unroll
        for (int r = 0; r < 4; ++r) {
            const int m = kl * 4 + r;
            h_out[(size_t)(n0 + m) * H + nA] = f2bf(acc0[r] + bA);
            h_out[(size_t)(n0 + m) * H + nB] = f2bf(acc1[r] + bB);
        }
    }
}

// ---------------------------------------------------------------------------
// CSR build (unchanged).
// ---------------------------------------------------------------------------
__global__ __launch_bounds__(256) void k_count(
    const int* __restrict__ ei, int* __restrict__ deg)
{
    const int e = blockIdx.x * 256 + threadIdx.x;
    if (e >= E_EDGES) return;
    atomicAdd(&deg[ei[E_EDGES + e]], 1);
}

__global__ __launch_bounds__(1024) void k_scan(
    int* __restrict__ off, int* __restrict__ cursor)
{
    const int t = threadIdx.x;
    const int CHUNK = (N_NODES + 1023) / 1024;
    const int lo = t * CHUNK;
    const int hi = min(lo + CHUNK, N_NODES);

    int mysum = 0;
    for (int i = lo; i < hi; ++i) mysum += off[i];

    __shared__ int s[1024];
    s[t] = mysum;
    __syncthreads();
    for (int d = 1; d < 1024; d <<= 1) {
        int v = (t >= d) ? s[t - d] : 0;
        __syncthreads();
        s[t] += v;
        __syncthreads();
    }
    int running = s[t] - mysum;

    for (int i = lo; i < hi; ++i) {
        const int d = off[i];
        off[i] = running;
        cursor[i] = running;
        running += d;
    }
    if (t == 0) off[N_NODES] = E_EDGES;
}

__global__ __launch_bounds__(256) void k_fill(
    const int* __restrict__ ei, const float* __restrict__ ea,
    int* __restrict__ cursor, int2* __restrict__ csr)
{
    const int e = blockIdx.x * 256 + threadIdx.x;
    if (e >= E_EDGES) return;
    const int dst = ei[E_EDGES + e];
    const int pos = atomicAdd(&cursor[dst], 1);
    csr[pos] = make_int2(ei[e], __float_as_int(ea[e]));
}

// ---------------------------------------------------------------------------
// k_layer: unchanged from round 1 (split-bf16 MFMA node update).
// ---------------------------------------------------------------------------
#define NPB 8
__global__ __launch_bounds__(256) void k_layer(
    const int* __restrict__ off, const int2* __restrict__ csr,
    const u16* __restrict__ h_in, u16* __restrict__ h_out,
    const float* __restrict__ ew, const float* __restrict__ eb,
    const float* __restrict__ eps_p,
    const u16* __restrict__ wh1, const u16* __restrict__ wl1,
    const float* __restrict__ b1, const float* __restrict__ bn_g,
    const float* __restrict__ bn_b, const float* __restrict__ bn_m,
    const float* __restrict__ bn_v,
    const u16* __restrict__ wh2, const u16* __restrict__ wl2,
    const float* __restrict__ b2,
    const int first_layer, const int last_layer,
    const float* __restrict__ aw, const float* __restrict__ ab,
    float* __restrict__ out)
{
    const int n0 = blockIdx.x * NPB;
    const int t  = threadIdx.x;

    __shared__ __align__(16) u16   s_zh[16 * 136];
    __shared__ __align__(16) u16   s_zl[16 * 136];
    __shared__ __align__(16) u16   s_th[16 * 136];
    __shared__ __align__(16) u16   s_tl[16 * 136];
    __shared__ __align__(16) float s_r [NPB * 128];
    __shared__ __align__(16) float s_hd[NPB * 128];

    const float ep1 = 1.f + eps_p[0];

    // ---- phase 1: gather. half-wave owns one node ----
    {
        const int lane = t & 63;
        const int half = lane >> 5;
        const int c = (lane & 31) * 4;
        const int np = t >> 6;
        const int q = np * 2 + half;
        const int n = n0 + q;

        const float4 wv = *(const float4*)&ew[c];
        const float4 bv = *(const float4*)&eb[c];

        int i        = off[n];
        const int hi = off[n + 1];

        float ax0 = 0.f, ay0 = 0.f, az0 = 0.f, aw0 = 0.f;
        float ax1 = 0.f, ay1 = 0.f, az1 = 0.f, aw1 = 0.f;

        for (; i + 7 < hi; i += 8) {
            int2 p[8];
            #pragma unroll
            for (int u = 0; u < 8; ++u) p[u] = csr[i + u];
            uint2 hq[8];
            #pragma unroll
            for (int u = 0; u < 8; ++u)
                hq[u] = *(const uint2*)&h_in[(size_t)p[u].x * H + c];
            #pragma unroll
            for (int u = 0; u < 8; ++u) {
                const float a = __int_as_float(p[u].y);
                const float h0 = bf_lo(hq[u].x), h1 = bf_hi(hq[u].x);
                const float h2 = bf_lo(hq[u].y), h3 = bf_hi(hq[u].y);
                if (u & 1) {
                    ax1 += fmaxf(fmaf(a, wv.x, h0) + bv.x, 0.f);
                    ay1 += fmaxf(fmaf(a, wv.y, h1) + bv.y, 0.f);
                    az1 += fmaxf(fmaf(a, wv.z, h2) + bv.z, 0.f);
                    aw1 += fmaxf(fmaf(a, wv.w, h3) + bv.w, 0.f);
                } else {
                    ax0 += fmaxf(fmaf(a, wv.x, h0) + bv.x, 0.f);
                    ay0 += fmaxf(fmaf(a, wv.y, h1) + bv.y, 0.f);
                    az0 += fmaxf(fmaf(a, wv.z, h2) + bv.z, 0.f);
                    aw0 += fmaxf(fmaf(a, wv.w, h3) + bv.w, 0.f);
                }
            }
        }
        for (; i < hi; ++i) {
            const int2 p0 = csr[i];
            const uint2 hq = *(const uint2*)&h_in[(size_t)p0.x * H + c];
            const float a0 = __int_as_float(p0.y);
            ax0 += fmaxf(fmaf(a0, wv.x, bf_lo(hq.x)) + bv.x, 0.f);
            ay0 += fmaxf(fmaf(a0, wv.y, bf_hi(hq.x)) + bv.y, 0.f);
            az0 += fmaxf(fmaf(a0, wv.z, bf_lo(hq.y)) + bv.z, 0.f);
            aw0 += fmaxf(fmaf(a0, wv.w, bf_hi(hq.y)) + bv.w, 0.f);
        }
        ax0 += ax1; ay0 += ay1; az0 += az1; aw0 += aw1;

        const uint2 ho = *(const uint2*)&h_in[(size_t)n * H + c];
        const float r0 = bf_lo(ho.x), r1 = bf_hi(ho.x);
        const float r2 = bf_lo(ho.y), r3 = bf_hi(ho.y);
        *(float4*)&s_r[q * 128 + c] = make_float4(r0, r1, r2, r3);

        const float z0 = fmaf(ep1, r0, ax0);
        const float z1 = fmaf(ep1, r1, ay0);
        const float z2 = fmaf(ep1, r2, az0);
        const float z3 = fmaf(ep1, r3, aw0);
        const u16 zh0 = f2bf(z0), zh1 = f2bf(z1), zh2 = f2bf(z2), zh3 = f2bf(z3);
        *(u32*)&s_zh[q * 136 + c]     = (u32)zh0 | ((u32)zh1 << 16);
        *(u32*)&s_zh[q * 136 + c + 2] = (u32)zh2 | ((u32)zh3 << 16);
        *(u32*)&s_zl[q * 136 + c]     = pack2bf(z0 - bfu(zh0), z1 - bfu(zh1));
        *(u32*)&s_zl[q * 136 + c + 2] = pack2bf(z2 - bfu(zh2), z3 - bfu(zh3));
    }
    __syncthreads();

    const int lane = t & 63;
    const int wv   = t >> 6;
    const int l15  = lane & 15;
    const int kl   = lane >> 4;
    const int nt0  = wv * 2, nt1 = wv * 2 + 1;
    const int nA   = nt0 * 16 + l15;
    const int nB   = nt1 * 16 + l15;

    // ---- phase 2: t = relu(BN(z @ w1 + b1))  [MFMA] ----
    {
        f32x4 acc0 = {0.f, 0.f, 0.f, 0.f};
        f32x4 acc1 = {0.f, 0.f, 0.f, 0.f};
        #pragma unroll
        for (int ks = 0; ks < 4; ++ks) {
            const int aoff = l15 * 136 + ks * 32 + kl * 8;
            const bf16x8 ah = *(const bf16x8*)&s_zh[aoff];
            const bf16x8 al = *(const bf16x8*)&s_zl[aoff];
            const int bo0 = (ks * 8 + nt0) * 512 + lane * 8;
            const int bo1 = (ks * 8 + nt1) * 512 + lane * 8;
            const bf16x8 bh0 = *(const bf16x8*)&wh1[bo0];
            const bf16x8 bl0 = *(const bf16x8*)&wl1[bo0];
            const bf16x8 bh1 = *(const bf16x8*)&wh1[bo1];
            const bf16x8 bl1 = *(const bf16x8*)&wl1[bo1];
            acc0 = MFMA16(ah, bh0, acc0);
            acc0 = MFMA16(al, bh0, acc0);
            acc0 = MFMA16(ah, bl0, acc0);
            acc1 = MFMA16(ah, bh1, acc1);
            acc1 = MFMA16(al, bh1, acc1);
            acc1 = MFMA16(ah, bl1, acc1);
        }
        const float sc0 = bn_g[nA] * rsqrtf(bn_v[nA] + BN_EPS);
        const float sh0 = fmaf(b1[nA] - bn_m[nA], sc0, bn_b[nA]);
        const float sc1 = bn_g[nB] * rsqrtf(bn_v[nB] + BN_EPS);
        const float sh1 = fmaf(b1[nB] - bn_m[nB], sc1, bn_b[nB]);

        if (kl < 2) {
            #pragma unroll
            for (int r = 0; r < 4; ++r) {
                const int m = kl * 4 + r;
                const float t0 = fmaxf(fmaf(acc0[r], sc0, sh0), 0.f);
                const float t1 = fmaxf(fmaf(acc1[r], sc1, sh1), 0.f);
                const u16 th0 = f2bf(t0), th1 = f2bf(t1);
                s_th[m * 136 + nA] = th0;
                s_tl[m * 136 + nA] = f2bf(t0 - bfu(th0));
                s_th[m * 136 + nB] = th1;
                s_tl[m * 136 + nB] = f2bf(t1 - bfu(th1));
            }
        }
    }
    __syncthreads();

    // ---- phase 3: c = t @ w2 + b2; h' = relu(c) (+res); store / head ----
    {
        f32x4 acc0 = {0.f, 0.f, 0.f, 0.f};
        f32x4 acc1 = {0.f, 0.f, 0.f, 0.f};
        #pragma unroll
        for (int ks = 0; ks < 4; ++ks) {
            const int aoff = l15 * 136 + ks * 32 + kl * 8;
            const bf16x8 ah = *(const bf16x8*)&s_th[aoff];
            const bf16x8 al = *(const bf16x8*)&s_tl[aoff];
            const int bo0 = (ks * 8 + nt0) * 512 + lane * 8;
            const int bo1 = (ks * 8 + nt1) * 512 + lane * 8;
            const bf16x8 bh0 = *(const bf16x8*)&wh2[bo0];
            const bf16x8 bl0 = *(const bf16x8*)&wl2[bo0];
            const bf16x8 bh1 = *(const bf16x8*)&wh2[bo1];
            const bf16x8 bl1 = *(const bf16x8*)&wl2[bo1];
            acc0 = MFMA16(ah, bh0, acc0);
            acc0 = MFMA16(al, bh0, acc0);
            acc0 = MFMA16(ah, bl0, acc0);
            acc1 = MFMA16(ah, bh1, acc1);
            acc1 = MFMA16(al, bh1, acc1);
            acc1 = MFMA16(ah, bl1, acc1);
        }
        const float bb0 = b2[nA];
        const float bb1 = b2[nB];

        if (kl < 2) {
            #pragma unroll
            for (int r = 0; r < 4; ++r) {
                const int m = kl * 4 + r;
                float h0 = fmaxf(acc0[r] + bb0, 0.f);
                float h1 = fmaxf(acc1[r] + bb1, 0.f);
                if (!first_layer) {
                    h0 += s_r[m * 128 + nA];
                    h1 += s_r[m * 128 + nB];
                }
                if (!last_layer) {
                    h_out[(size_t)(n0 + m) * H + nA] = f2bf(h0);
                    h_out[(size_t)(n0 + m) * H + nB] = f2bf(h1);
                } else {
                    s_hd[m * 128 + nA] = h0;
                    s_hd[m * 128 + nB] = h1;
                }
            }
        }
    }

    if (last_layer) {
        __syncthreads();
        const int jp = t & 63;  const int j0 = jp * 2;
        const int np = t >> 6;  const int na = np * 2, nb = na + 1;
        const float2 ha  = *(const float2*)&s_hd[na * 128 + j0];
        const float2 hbv = *(const float2*)&s_hd[nb * 128 + j0];
        const float2 awx = *(const float2*)&aw[j0 * 2];
        const float2 awy = *(const float2*)&aw[(j0 + 1) * 2];
        float mu_a = ha.x  * awx.x + ha.y  * awy.x;
        float sg_a = ha.x  * awx.y + ha.y  * awy.y;
        float mu_b = hbv.x * awx.x + hbv.y * awy.x;
        float sg_b = hbv.x * awx.y + hbv.y * awy.y;
        #pragma unroll
        for (int sft = 32; sft > 0; sft >>= 1) {
            mu_a += __shfl_down(mu_a, sft);
            sg_a += __shfl_down(sg_a, sft);
            mu_b += __shfl_down(mu_b, sft);
            sg_b += __shfl_down(sg_b, sft);
        }
        if (jp == 0) {
            const float o1a = sg_a + ab[1];
            const float o1b = sg_b + ab[1];
            const float spa = (o1a > 0.f) ? (o1a + log1pf(expf(-o1a)))
                                          : log1pf(expf(o1a));
            const float spb = (o1b > 0.f) ? (o1b + log1pf(expf(-o1b)))
                                          : log1pf(expf(o1b));
            out[(size_t)(n0 + na) * 2 + 0] = mu_a + ab[0];
            out[(size_t)(n0 + na) * 2 + 1] = spa;
            out[(size_t)(n0 + nb) * 2 + 0] = mu_b + ab[0];
            out[(size_t)(n0 + nb) * 2 + 1] = spb;
        }
    }
}

// ---------------------------------------------------------------------------
extern "C" void kernel_launch(void* const* d_in, const int* in_sizes, int n_in,
                              void* d_out, int out_size, void* d_ws, size_t ws_size,
                              hipStream_t stream)
{
    const float* ensemble = (const float*)d_in[0];
    const float* x        = (const float*)d_in[1];
    const int*   ei       = (const int*)d_in[2];
    const float* ea       = (const float*)d_in[3];
    const float* phi_w1   = (const float*)d_in[4];
    const float* phi_b1   = (const float*)d_in[5];
    const float* phi_w2   = (const float*)d_in[6];
    const float* phi_b2   = (const float*)d_in[7];
    const float* rho_w1   = (const float*)d_in[8];
    const float* rho_b1   = (const float*)d_in[9];
    const float* rho_w2   = (const float*)d_in[10];
    const float* rho_b2   = (const float*)d_in[11];
    const float* dr_w     = (const float*)d_in[12];
    const float* dr_b     = (const float*)d_in[13];
    const float* conv_eps = (const float*)d_in[14];
    const float* edge_w   = (const float*)d_in[15];
    const float* edge_b   = (const float*)d_in[16];
    const float* mlp_w1   = (const float*)d_in[17];
    const float* mlp_b1   = (const float*)d_in[18];
    const float* bn_g     = (const float*)d_in[19];
    const float* bn_b     = (const float*)d_in[20];
    const float* bn_m     = (const float*)d_in[21];
    const float* bn_v     = (const float*)d_in[22];
    const float* mlp_w2   = (const float*)d_in[23];
    const float* mlp_b2   = (const float*)d_in[24];
    const float* aggr_w   = (const float*)d_in[25];
    const float* aggr_b   = (const float*)d_in[26];

    float* out = (float*)d_out;

    // workspace layout
    float* Wf1     = (float*)d_ws;                          // H*H
    float* bf1     = Wf1 + H * H;                           // H
    float* Wf2     = bf1 + H;                               // H*H
    float* bf2     = Wf2 + H * H;                           // H
    int*   off     = (int*)(bf2 + H);                       // N+2 (padded)
    int*   cursor  = off + (N_NODES + 2);                   // N
    int2*  csr     = (int2*)(cursor + N_NODES);             // E (8B aligned)
    u16*   h_a     = (u16*)(csr + E_EDGES);                 // N*H bf16
    u16*   h_b     = h_a + (size_t)N_NODES * H;             // N*H bf16
    u16*   wpk     = h_b + (size_t)N_NODES * H;             // 196608 u16
    u16*   wpk2    = wpk + 196608;                          // 81920 u16

    const int eblocks = (E_EDGES + 255) / 256;

    // fold weights, pack MFMA weights, then embed -> h_a
    k_fold<<<256, 256, 0, stream>>>(phi_w2, phi_b2, rho_w1, rho_b1,
                                    rho_w2, rho_b2, dr_w, dr_b,
                                    Wf1, bf1, Wf2, bf2);
    k_pack<<<384, 256, 0, stream>>>(mlp_w1, mlp_w2, wpk);
    k_pack2<<<160, 256, 0, stream>>>(phi_w1, Wf1, Wf2, dr_w, wpk2);
    k_embed<<<N_NODES / ENB, 256, 0, stream>>>(
        ensemble, x, phi_b1, bf1, bf2, wpk2, h_a);

    // CSR build (once)
    hipMemsetAsync(off, 0, (N_NODES + 1) * sizeof(int), stream);
    k_count<<<eblocks, 256, 0, stream>>>(ei, off);
    k_scan<<<1, 1024, 0, stream>>>(off, cursor);
    k_fill<<<eblocks, 256, 0, stream>>>(ei, ea, cursor, csr);

    // fused GINE layers (double-buffered h; last layer writes head to out)
    u16* hin = h_a; u16* hout = h_b;
    for (int i = 0; i < L_LAYERS; ++i) {
        const u16* wh1 = wpk + ((size_t)i * 2 + 0) * 32768;
        const u16* wl1 = wh1 + 16384;
        const u16* wh2 = wpk + ((size_t)i * 2 + 1) * 32768;
        const u16* wl2 = wh2 + 16384;
        k_layer<<<N_NODES / NPB, 256, 0, stream>>>(
            off, csr, hin, hout,
            edge_w + (size_t)i * H, edge_b + (size_t)i * H, conv_eps + i,
            wh1, wl1,
            mlp_b1 + (size_t)i * H,
            bn_g + (size_t)i * H, bn_b + (size_t)i * H,
            bn_m + (size_t)i * H, bn_v + (size_t)i * H,
            wh2, wl2, mlp_b2 + (size_t)i * H,
            (i == 0) ? 1 : 0, (i == L_LAYERS - 1) ? 1 : 0,
            aggr_w, aggr_b, out);
        u16* tmp = hin; hin = hout; hout = tmp;
    }
}